// Round 15
// baseline (275.832 us; speedup 1.0000x reference)
//
#include <hip/hip_runtime.h>
#include <stdint.h>
#include <stddef.h>

using short8 = __attribute__((ext_vector_type(8))) short;
using short4v = __attribute__((ext_vector_type(4))) short;
using f32x4  = __attribute__((ext_vector_type(4))) float;
using f32x16 = __attribute__((ext_vector_type(16))) float;
using bf16x8 = __attribute__((ext_vector_type(8))) __bf16;

#define DEVI __device__ __forceinline__

// round-to-nearest-even fp32 -> bf16 (bit pattern as short)
DEVI short bf16r(float f) {
  union { float f; uint32_t u; } x; x.f = f;
  uint32_t r = x.u + 0x7FFFu + ((x.u >> 16) & 1u);
  return (short)(r >> 16);
}

DEVI f32x4 mfma16(short8 a, short8 b, f32x4 c) {
  return __builtin_amdgcn_mfma_f32_16x16x32_bf16(
      __builtin_bit_cast(bf16x8, a), __builtin_bit_cast(bf16x8, b), c, 0, 0, 0);
}

DEVI f32x16 mfma32(short8 a, short8 b, f32x16 c) {
  return __builtin_amdgcn_mfma_f32_32x32x16_bf16(
      __builtin_bit_cast(bf16x8, a), __builtin_bit_cast(bf16x8, b), c, 0, 0, 0);
}

DEVI void gload_lds16(const void* g, void* l) {
  __builtin_amdgcn_global_load_lds(
      (const void __attribute__((address_space(1)))*)g,
      (void __attribute__((address_space(3)))*)l,
      16, 0, 0);
}

// v_exp_f32 computes 2^x
DEVI float fexp2(float x) {
  float r;
  asm("v_exp_f32 %0, %1" : "=v"(r) : "v"(x));
  return r;
}

// packed fp32->bf16: dst[15:0]=bf16(a), dst[31:16]=bf16(b)
DEVI unsigned cvtpk(float a, float b) {
  unsigned r;
  asm("v_cvt_pk_bf16_f32 %0, %1, %2" : "=v"(r) : "v"(a), "v"(b));
  return r;
}

// LEDGER (session-wide, do not re-try without new theory/hardware probe):
//  * v_permlane32_swap_b32 via inline asm: POISONED — failed BOTH operand
//    orders (R2 absmax 0.575, R14 absmax 0.628). Suspect copy+swap reduce
//    idiom lets regalloc alias the two identical "+v" operands. Use
//    __shfl_xor(.,32) (ds_bpermute) — proven green R3/R8/R9/R13.

// ---------------- fp32 -> bf16 conversions ----------------
// 4 weight tensors in one dispatch: z in 0..3; z<2 big (n_big), z>=2 small (n_small)
__global__ void k_cvtw(const float* __restrict__ s0, short* __restrict__ d0,
                       const float* __restrict__ s1, short* __restrict__ d1,
                       const float* __restrict__ s2, short* __restrict__ d2,
                       const float* __restrict__ s3, short* __restrict__ d3,
                       int n_big, int n_small) {
  const int z = blockIdx.z;
  const float* s = (z == 0) ? s0 : (z == 1) ? s1 : (z == 2) ? s2 : s3;
  short* d = (z == 0) ? d0 : (z == 1) ? d1 : (z == 2) ? d2 : d3;
  const int n = (z < 2) ? n_big : n_small;
  int i = blockIdx.x * blockDim.x + threadIdx.x;
  if (i < n) {
    f32x4 v = reinterpret_cast<const f32x4*>(s)[i];
    short4v o;
    o[0] = bf16r(v[0]); o[1] = bf16r(v[1]); o[2] = bf16r(v[2]); o[3] = bf16r(v[3]);
    reinterpret_cast<short4v*>(d)[i] = o;
  }
}

// 3 activation tensors (query/key/value), same size, z selects
__global__ void k_cvta(const float* __restrict__ s0, short* __restrict__ d0,
                       const float* __restrict__ s1, short* __restrict__ d1,
                       const float* __restrict__ s2, short* __restrict__ d2, int n4) {
  const int z = blockIdx.z;
  const float* s = (z == 0) ? s0 : (z == 1) ? s1 : s2;
  short* d = (z == 0) ? d0 : (z == 1) ? d1 : d2;
  int i = blockIdx.x * blockDim.x + threadIdx.x;
  if (i < n4) {
    f32x4 v = reinterpret_cast<const f32x4*>(s)[i];
    short4v o;
    o[0] = bf16r(v[0]); o[1] = bf16r(v[1]); o[2] = bf16r(v[2]); o[3] = bf16r(v[3]);
    reinterpret_cast<short4v*>(d)[i] = o;
  }
}

// ---------------- GEMM: C(M,N) = (A(M,K)bf16 @ W(N,K)^T + bias) * alpha ----------------
// Inner loop = R9's green kernel, unchanged. NSEL=1: single GEMM (set 0).
// NSEL=3: blockIdx.z selects set 0 (N=N0,alpha=alpha0) or sets 1/2 (N=N12,
// alpha=alpha12); out-of-range blocks exit before any barrier (uniform).
template<bool OUT_F32, int NSEL>
__global__ __launch_bounds__(256) void k_gemm(
    const short* __restrict__ Aw, const short* __restrict__ Bw,
    const float* __restrict__ bias, void* __restrict__ Cp,
    const short* __restrict__ Aw2, const short* __restrict__ Bw2,
    const float* __restrict__ bias2, void* __restrict__ Cp2,
    const short* __restrict__ Aw3, const short* __restrict__ Bw3,
    const float* __restrict__ bias3, void* __restrict__ Cp3,
    int M, int K, int N0, float alpha0, int N12, float alpha12)
{
  int N = N0;
  float alpha = alpha0;
  if constexpr (NSEL == 3) {
    const int z = blockIdx.z;
    if (z == 1) { Aw = Aw2; Bw = Bw2; bias = bias2; Cp = Cp2; N = N12; alpha = alpha12; }
    else if (z == 2) { Aw = Aw3; Bw = Bw3; bias = bias3; Cp = Cp3; N = N12; alpha = alpha12; }
    if ((int)blockIdx.x * 128 >= N) return;   // uniform whole-block exit, pre-barrier
  }
  __shared__ short As[2][128 * 64];
  __shared__ short Bs[2][128 * 64];
  const int t = threadIdx.x;
  const int lane = t & 63;
  const int wid = t >> 6;
  const int wr = wid >> 1, wc = wid & 1;
  const int bm = blockIdx.y * 128;
  const int bn = blockIdx.x * 128;

  f32x4 acc[4][4];
  #pragma unroll
  for (int i = 0; i < 4; ++i)
    #pragma unroll
    for (int j = 0; j < 4; ++j) acc[i][j] = f32x4{0.f, 0.f, 0.f, 0.f};

  const int nt = K >> 6;

  auto stage = [&](const short* G, short (&buf)[128 * 64], int k0) {
    #pragma unroll
    for (int i = 0; i < 4; ++i) {
      int lin = t * 16 + i * 4096;
      int a = lin ^ (((lin >> 7) & 7) << 4);
      int row = a >> 7;
      int col = (a & 127) >> 1;
      const short* g = G + (size_t)row * K + k0 + col;
      gload_lds16(g, (char*)(&buf[0]) + (wid << 10) + (i << 12));
    }
  };

  stage(Aw + (size_t)bm * K, As[0], 0);
  stage(Bw + (size_t)bn * K, Bs[0], 0);
  __syncthreads();

  int cur = 0;
  for (int kt = 0; kt < nt; ++kt) {
    const bool pf = (kt + 1 < nt);
    if (pf) {
      stage(Aw + (size_t)bm * K, As[cur ^ 1], (kt + 1) << 6);
      stage(Bw + (size_t)bn * K, Bs[cur ^ 1], (kt + 1) << 6);
    }
    #pragma unroll
    for (int kk = 0; kk < 2; ++kk) {
      const int kb = (kk * 32 + ((lane >> 4) << 3)) << 1;
      short8 af[4], bfr[4];
      #pragma unroll
      for (int i = 0; i < 4; ++i) {
        int row = wr * 64 + i * 16 + (lane & 15);
        int byte = ((row << 7) + kb) ^ ((row & 7) << 4);
        af[i] = *reinterpret_cast<const short8*>((const char*)(&As[cur][0]) + byte);
      }
      #pragma unroll
      for (int j = 0; j < 4; ++j) {
        int row = wc * 64 + j * 16 + (lane & 15);
        int byte = ((row << 7) + kb) ^ ((row & 7) << 4);
        bfr[j] = *reinterpret_cast<const short8*>((const char*)(&Bs[cur][0]) + byte);
      }
      __builtin_amdgcn_s_setprio(1);
      #pragma unroll
      for (int i = 0; i < 4; ++i)
        #pragma unroll
        for (int j = 0; j < 4; ++j)
          acc[i][j] = mfma16(af[i], bfr[j], acc[i][j]);
      __builtin_amdgcn_s_setprio(0);
    }
    __syncthreads();
    cur ^= 1;
  }

  #pragma unroll
  for (int j = 0; j < 4; ++j) {
    int col = bn + wc * 64 + j * 16 + (lane & 15);
    float bv = bias[col];
    #pragma unroll
    for (int i = 0; i < 4; ++i) {
      int row0 = bm + wr * 64 + i * 16 + ((lane >> 4) << 2);
      #pragma unroll
      for (int r = 0; r < 4; ++r) {
        float v = (acc[i][j][r] + bv) * alpha;
        if constexpr (OUT_F32)
          ((float*)Cp)[(size_t)(row0 + r) * N + col] = v;
        else
          ((short*)Cp)[(size_t)(row0 + r) * N + col] = bf16r(v);
      }
    }
  }
}

// ---------------- flash attention, 8-warp swapped-QK^T (R13 VERBATIM — green) ----------------
// Q: (B,T,H*64) bf16 pre-scaled by SCALE*log2e. K/V: (B,T,G*64) bf16. O: (B,T,H*64) bf16.
// Per block: 256 q-rows (8 warps x 32), KVBLK=64, 32x32x16 MFMA.
// S^T = mfma(K, Q): col=q=lane&31 -> lane-local softmax state (m,l).
// LEDGER — refuted changes to this kernel (do not re-try without new theory):
//  * fixed-m=0 softmax: FAILS here (R5-R7, absmax ~0.04; passes in 4-warp R4)
//  * S-ahead pipeline: VGPR spill, +11MB scratch traffic (R10, 112 µs)
//  * s_setprio around MFMA: barrier-lockstep -> occupancy loss (R11, ~+7 µs)
//  * tree max/sum reductions: +4 VGPR crosses the 64-VGPR cliff (m69),
//    waves/CU ceiling halves, occupancy 35->21% (R12, +18 µs)
//  * permlane32_swap (asm) for pack/reduce: wrong results both operand
//    orders (R2 0.575, R14 0.628) — POISONED.
//  This kernel sits EXACTLY at VGPR=64 — any change costing registers loses.
__global__ __launch_bounds__(512) void k_attn(
    const short* __restrict__ Q, const short* __restrict__ Kg,
    const short* __restrict__ Vg, short* __restrict__ Op)
{
  constexpr int T = 2048;
  constexpr int NT = T / 64;

  // bijective XCD-chunked swizzle: 512 blocks -> 64 contiguous per XCD
  const int orig = blockIdx.x;
  const int wgid = (orig & 7) * 64 + (orig >> 3);
  const int bh = wgid >> 3;            // 0..63 = b*32+h
  const int qb = wgid & 7;
  const int b = bh >> 5, h = bh & 31;
  const int g = h >> 2;
  const int q0 = qb * 256;

  const int t = threadIdx.x;
  const int lane = t & 63;
  const int wid = t >> 6;
  const int lo = lane & 31;
  const int hi = lane >> 5;

  __shared__ alignas(16) union {
    struct {
      short Kl[2][64 * 64];   // [key][d], XOR-swizzled bytes, gload_lds staged
      short Vt[2][64 * 72];   // [d][key], stride 72, reg-staged transpose
    } s;
    short Ol[8][32 * 72];     // epilogue O transpose, per-warp
  } sm;

  // Q fragments (B-operand): lane holds Q[q0w+lo][s*16 + hi*8 .. +8]
  const size_t qrow = (size_t)(b * T + q0 + wid * 32 + lo);
  short8 qf[4];
  #pragma unroll
  for (int s = 0; s < 4; ++s)
    qf[s] = *reinterpret_cast<const short8*>(Q + qrow * 2048 + h * 64 + s * 16 + hi * 8);

  f32x16 o0, o1;
  #pragma unroll
  for (int r = 0; r < 16; ++r) { o0[r] = 0.f; o1[r] = 0.f; }
  float m = -10000.f, l = 0.f;

  const short* Kbase = Kg + (size_t)(b * T) * 512 + g * 64;
  const short* Vbase = Vg + (size_t)(b * T) * 512 + g * 64;

  auto stageK = [&](int buf, int k0) {
    int lin = t * 16;                            // linear LDS byte dest
    int a = lin ^ (((lin >> 7) & 7) << 4);       // inverse-swizzled logical src
    int row = a >> 7;
    int col = (a & 127) >> 1;
    gload_lds16(Kbase + (size_t)(k0 + row) * 512 + col,
                (char*)(&sm.s.Kl[buf][0]) + (wid << 10));
  };
  short8 vreg;
  auto loadV = [&](int k0) {
    // thread t: key=lane, d-chunk=wid*8 (16B per lane)
    vreg = *reinterpret_cast<const short8*>(
        Vbase + (size_t)(k0 + lane) * 512 + wid * 8);
  };
  auto writeV = [&](int buf) {
    // V^T[d][key]: lanes write consecutive keys -> conflict-free
    #pragma unroll
    for (int e = 0; e < 8; ++e)
      sm.s.Vt[buf][(wid * 8 + e) * 72 + lane] = vreg[e];
  };

  stageK(0, 0);
  loadV(0);
  writeV(0);
  __syncthreads();

  int cur = 0;
  for (int kt = 0; kt < NT; ++kt) {
    const bool pf = (kt + 1 < NT);
    if (pf) { stageK(cur ^ 1, (kt + 1) * 64); loadV((kt + 1) * 64); }

    // ---- K frags (A-operand) + QK^T ----
    short8 kf[2][4];
    #pragma unroll
    for (int tt = 0; tt < 2; ++tt)
      #pragma unroll
      for (int s = 0; s < 4; ++s) {
        int row = tt * 32 + lo;
        int byte = ((row << 7) + (s << 5) + (hi << 4)) ^ ((row & 7) << 4);
        kf[tt][s] = *reinterpret_cast<const short8*>((const char*)(&sm.s.Kl[cur][0]) + byte);
      }
    f32x16 st0, st1;
    #pragma unroll
    for (int r = 0; r < 16; ++r) { st0[r] = 0.f; st1[r] = 0.f; }
    #pragma unroll
    for (int s = 0; s < 4; ++s) {
      st0 = mfma32(kf[0][s], qf[s], st0);
      st1 = mfma32(kf[1][s], qf[s], st1);
    }

    // ---- online softmax (log2 domain), lane-local q ----
    float mx = st0[0];
    #pragma unroll
    for (int r = 1; r < 16; ++r) mx = fmaxf(mx, st0[r]);
    #pragma unroll
    for (int r = 0; r < 16; ++r) mx = fmaxf(mx, st1[r]);
    mx = fmaxf(mx, __shfl_xor(mx, 32));
    if (!__all(mx - m <= 8.0f)) {      // T13 defer-max
      float mn = fmaxf(m, mx);
      float sc = fexp2(m - mn);
      m = mn; l *= sc;
      o0 = o0 * sc; o1 = o1 * sc;
    }
    float ssum = 0.f;
    #pragma unroll
    for (int r = 0; r < 16; ++r) { float e = fexp2(st0[r] - m); st0[r] = e; ssum += e; }
    #pragma unroll
    for (int r = 0; r < 16; ++r) { float e = fexp2(st1[r] - m); st1[r] = e; ssum += e; }
    ssum += __shfl_xor(ssum, 32);
    l += ssum;

    // ---- P -> bf16 B-frags: cvt_pk + cross-half shfl_xor redistribution ----
    short8 pb[4];
    #pragma unroll
    for (int tt = 0; tt < 2; ++tt) {
      const f32x16& sv = tt ? st1 : st0;
      #pragma unroll
      for (int half = 0; half < 2; ++half) {
        unsigned x1 = cvtpk(sv[half * 8 + 0], sv[half * 8 + 1]);
        unsigned x2 = cvtpk(sv[half * 8 + 2], sv[half * 8 + 3]);
        unsigned x3 = cvtpk(sv[half * 8 + 4], sv[half * 8 + 5]);
        unsigned x4 = cvtpk(sv[half * 8 + 6], sv[half * 8 + 7]);
        unsigned y1 = __shfl_xor(x1, 32);
        unsigned y2 = __shfl_xor(x2, 32);
        unsigned y3 = __shfl_xor(x3, 32);
        unsigned y4 = __shfl_xor(x4, 32);
        union { unsigned u[4]; short8 s8; } p;
        p.u[0] = hi ? y3 : x1;
        p.u[1] = hi ? y4 : x2;
        p.u[2] = hi ? x3 : y1;
        p.u[3] = hi ? x4 : y2;
        pb[tt * 2 + half] = p.s8;
      }
    }

    // ---- V^T frags (A-operand) + PV ----
    #pragma unroll
    for (int ks = 0; ks < 4; ++ks) {
      {
        int byte = (lo * 144) + (ks << 5) + (hi << 4);
        short8 va = *reinterpret_cast<const short8*>((const char*)(&sm.s.Vt[cur][0]) + byte);
        o0 = mfma32(va, pb[ks], o0);
      }
      {
        int byte = ((32 + lo) * 144) + (ks << 5) + (hi << 4);
        short8 va = *reinterpret_cast<const short8*>((const char*)(&sm.s.Vt[cur][0]) + byte);
        o1 = mfma32(va, pb[ks], o1);
      }
    }

    if (pf) writeV(cur ^ 1);
    __syncthreads();
    cur ^= 1;
  }

  // ---- epilogue: normalize, transpose via LDS, coalesced store ----
  float inv = 1.0f / l;
  #pragma unroll
  for (int dt = 0; dt < 2; ++dt) {
    const f32x16& ov = dt ? o1 : o0;
    #pragma unroll
    for (int r = 0; r < 16; r += 2) {
      unsigned d2 = cvtpk(ov[r] * inv, ov[r + 1] * inv);
      int dpos = dt * 32 + (r & 3) + 8 * (r >> 2) + 4 * hi;   // even
      *reinterpret_cast<unsigned*>((char*)(&sm.Ol[wid][0]) + (lo * 72 + dpos) * 2) = d2;
    }
  }
  __syncthreads();
  #pragma unroll
  for (int i = 0; i < 4; ++i) {
    int c = hi * 4 + i;
    short8 v = *reinterpret_cast<const short8*>((const char*)(&sm.Ol[wid][0]) + lo * 144 + c * 16);
    *reinterpret_cast<short8*>(Op + qrow * 2048 + h * 64 + c * 8) = v;
  }
}

// ---------------- launch ----------------
// Workspace (62914560 B):
//   [0..8M) q_wb  [8M..10M) k_wb  [10M..12M) v_wb  [12M..20M) o_wb
//   R1 [20M..36M): kx -> Ap (attn out)
//   R2 [36M..52M): vx
//   [52M..56M) Kp   [56M..60M) Vp
// d_out (33.5 MB fp32 out) doubles as scratch BEFORE O-proj:
//   qx = d_out[0..16M) bf16, Qp = d_out[16M..32M) bf16 — O-proj fully overwrites.
// Q-proj + K-proj + V-proj run as ONE dispatch (NSEL=3): 768 active blocks in
// one pool (~3/CU) instead of two serial dispatches (graph replays preserve
// stream order, so separate dispatches never overlap).
extern "C" void kernel_launch(void* const* d_in, const int* in_sizes, int n_in,
                              void* d_out, int out_size, void* d_ws, size_t ws_size,
                              hipStream_t stream)
{
  const float* query = (const float*)d_in[0];
  const float* key   = (const float*)d_in[1];
  const float* value = (const float*)d_in[2];
  const float* q_w   = (const float*)d_in[3];
  const float* q_b   = (const float*)d_in[4];
  const float* k_w   = (const float*)d_in[5];
  const float* k_b   = (const float*)d_in[6];
  const float* v_w   = (const float*)d_in[7];
  const float* v_b   = (const float*)d_in[8];
  const float* o_w   = (const float*)d_in[9];
  const float* o_b   = (const float*)d_in[10];
  float* out = (float*)d_out;

  char* ws = (char*)d_ws;
  short* q_wb = (short*)(ws);
  short* k_wb = (short*)(ws + 8388608);
  short* v_wb = (short*)(ws + 10485760);
  short* o_wb = (short*)(ws + 12582912);
  short* R1   = (short*)(ws + 20971520);   // kx -> Ap
  short* R2   = (short*)(ws + 37748736);   // vx
  short* Kp   = (short*)(ws + 54525952);
  short* Vp   = (short*)(ws + 58720256);

  short* qx = (short*)d_out;                       // 16777216 B
  short* Qp = (short*)((char*)d_out + 16777216);   // 16777216 B

  const float ALPHA_Q = 0.125f * 1.4426950408889634f;  // SCALE * log2(e)

  // all 4 weight cvts in one dispatch; all 3 activation cvts in one dispatch
  k_cvtw<<<dim3(4096, 1, 4), 256, 0, stream>>>(
      q_w, q_wb, o_w, o_wb, k_w, k_wb, v_w, v_wb, 1048576, 262144);
  k_cvta<<<dim3(8192, 1, 3), 256, 0, stream>>>(
      query, qx, key, R1, value, R2, 2097152);

  // fused Q-proj / K-proj / V-proj (one dispatch, z selects)
  k_gemm<false, 3><<<dim3(16, 32, 3), 256, 0, stream>>>(
      qx, q_wb, q_b, Qp,
      R1, k_wb, k_b, Kp,
      R2, v_wb, v_b, Vp,
      4096, 2048, 2048, ALPHA_Q, 512, 1.0f);

  // attention (Qp@d_out, Kp, Vp -> Ap@R1; kx dead)
  k_attn<<<dim3(512), dim3(512), 0, stream>>>(Qp, Kp, Vp, R1);

  // O-proj (Ap@R1 -> out; overwrites ALL of d_out)
  k_gemm<true, 1><<<dim3(16, 32), 256, 0, stream>>>(
      R1, o_wb, o_b, out,
      nullptr, nullptr, nullptr, nullptr,
      nullptr, nullptr, nullptr, nullptr,
      4096, 2048, 2048, 1.0f, 0, 0.f);
}

// Round 16
// 256.171 us; speedup vs baseline: 1.0767x; 1.0767x over previous
//
#include <hip/hip_runtime.h>
#include <stdint.h>
#include <stddef.h>

using short8 = __attribute__((ext_vector_type(8))) short;
using short4v = __attribute__((ext_vector_type(4))) short;
using f32x4  = __attribute__((ext_vector_type(4))) float;
using f32x16 = __attribute__((ext_vector_type(16))) float;
using bf16x8 = __attribute__((ext_vector_type(8))) __bf16;

#define DEVI __device__ __forceinline__

// SESSION LEDGER (refuted — do not re-try without new theory/hardware probe):
//  * v_permlane32_swap_b32 inline asm: failed BOTH operand orders (R2 0.575,
//    R14 0.628). Use __shfl_xor(.,32) — green R3/R8/R9/R13.
//  * fixed-m=0 softmax in 8-warp attn: fails ~0.04 (R5-R7); fine in 4-warp (R4).
//  * attn S-ahead pipeline: VGPR spill (R10). attn setprio: lockstep loss (R11).
//  * attn tree reductions: +4 VGPR crosses 64-VGPR cliff, occ 35->21% (R12).
//  * QKV GEMM merge (one dispatch): L2 thrash, FETCH 40->137MB, 71->116 µs (R15).
//    Elementwise cvt merges are safe (no L2 reuse window to destroy).

// round-to-nearest-even fp32 -> bf16 (bit pattern as short)
DEVI short bf16r(float f) {
  union { float f; uint32_t u; } x; x.f = f;
  uint32_t r = x.u + 0x7FFFu + ((x.u >> 16) & 1u);
  return (short)(r >> 16);
}

DEVI f32x4 mfma16(short8 a, short8 b, f32x4 c) {
  return __builtin_amdgcn_mfma_f32_16x16x32_bf16(
      __builtin_bit_cast(bf16x8, a), __builtin_bit_cast(bf16x8, b), c, 0, 0, 0);
}

DEVI f32x16 mfma32(short8 a, short8 b, f32x16 c) {
  return __builtin_amdgcn_mfma_f32_32x32x16_bf16(
      __builtin_bit_cast(bf16x8, a), __builtin_bit_cast(bf16x8, b), c, 0, 0, 0);
}

DEVI void gload_lds16(const void* g, void* l) {
  __builtin_amdgcn_global_load_lds(
      (const void __attribute__((address_space(1)))*)g,
      (void __attribute__((address_space(3)))*)l,
      16, 0, 0);
}

// v_exp_f32 computes 2^x
DEVI float fexp2(float x) {
  float r;
  asm("v_exp_f32 %0, %1" : "=v"(r) : "v"(x));
  return r;
}

// packed fp32->bf16: dst[15:0]=bf16(a), dst[31:16]=bf16(b)
DEVI unsigned cvtpk(float a, float b) {
  unsigned r;
  asm("v_cvt_pk_bf16_f32 %0, %1, %2" : "=v"(r) : "v"(a), "v"(b));
  return r;
}

// ---------------- fp32 -> bf16 conversion: ALL 7 tensors, one dispatch ----------------
// z: 0=q_w 1=o_w (n=1048576), 2=k_w 3=v_w (n=262144), 4=query 5=key 6=value (n=2097152).
// Independent elementwise streams — no L2-reuse window, safe to merge (cf. R15 GEMM lesson).
__global__ void k_cvt7(const float* __restrict__ s0, short* __restrict__ d0,
                       const float* __restrict__ s1, short* __restrict__ d1,
                       const float* __restrict__ s2, short* __restrict__ d2,
                       const float* __restrict__ s3, short* __restrict__ d3,
                       const float* __restrict__ s4, short* __restrict__ d4,
                       const float* __restrict__ s5, short* __restrict__ d5,
                       const float* __restrict__ s6, short* __restrict__ d6) {
  const int z = blockIdx.z;
  const float* s = (z == 0) ? s0 : (z == 1) ? s1 : (z == 2) ? s2 : (z == 3) ? s3
                 : (z == 4) ? s4 : (z == 5) ? s5 : s6;
  short* d = (z == 0) ? d0 : (z == 1) ? d1 : (z == 2) ? d2 : (z == 3) ? d3
           : (z == 4) ? d4 : (z == 5) ? d5 : d6;
  const int n = (z < 2) ? 1048576 : (z < 4) ? 262144 : 2097152;
  int i = blockIdx.x * blockDim.x + threadIdx.x;
  if (i < n) {
    f32x4 v = reinterpret_cast<const f32x4*>(s)[i];
    short4v o;
    o[0] = bf16r(v[0]); o[1] = bf16r(v[1]); o[2] = bf16r(v[2]); o[3] = bf16r(v[3]);
    reinterpret_cast<short4v*>(d)[i] = o;
  }
}

// ---------------- GEMM: C(M,N) = (A(M,K)bf16 @ W(N,K)^T + bias) * alpha ----------------
// [R9 verbatim — green]
template<bool OUT_F32, bool DUAL>
__global__ __launch_bounds__(256) void k_gemm(
    const short* __restrict__ Aw, const short* __restrict__ Bw,
    const float* __restrict__ bias, void* __restrict__ Cp,
    const short* __restrict__ Aw2, const short* __restrict__ Bw2,
    const float* __restrict__ bias2, void* __restrict__ Cp2,
    int M, int N, int K, float alpha)
{
  if constexpr (DUAL) {
    if (blockIdx.z) { Aw = Aw2; Bw = Bw2; bias = bias2; Cp = Cp2; }
  }
  __shared__ short As[2][128 * 64];
  __shared__ short Bs[2][128 * 64];
  const int t = threadIdx.x;
  const int lane = t & 63;
  const int wid = t >> 6;
  const int wr = wid >> 1, wc = wid & 1;
  const int bm = blockIdx.y * 128;
  const int bn = blockIdx.x * 128;

  f32x4 acc[4][4];
  #pragma unroll
  for (int i = 0; i < 4; ++i)
    #pragma unroll
    for (int j = 0; j < 4; ++j) acc[i][j] = f32x4{0.f, 0.f, 0.f, 0.f};

  const int nt = K >> 6;

  auto stage = [&](const short* G, short (&buf)[128 * 64], int k0) {
    #pragma unroll
    for (int i = 0; i < 4; ++i) {
      int lin = t * 16 + i * 4096;
      int a = lin ^ (((lin >> 7) & 7) << 4);
      int row = a >> 7;
      int col = (a & 127) >> 1;
      const short* g = G + (size_t)row * K + k0 + col;
      gload_lds16(g, (char*)(&buf[0]) + (wid << 10) + (i << 12));
    }
  };

  stage(Aw + (size_t)bm * K, As[0], 0);
  stage(Bw + (size_t)bn * K, Bs[0], 0);
  __syncthreads();

  int cur = 0;
  for (int kt = 0; kt < nt; ++kt) {
    const bool pf = (kt + 1 < nt);
    if (pf) {
      stage(Aw + (size_t)bm * K, As[cur ^ 1], (kt + 1) << 6);
      stage(Bw + (size_t)bn * K, Bs[cur ^ 1], (kt + 1) << 6);
    }
    #pragma unroll
    for (int kk = 0; kk < 2; ++kk) {
      const int kb = (kk * 32 + ((lane >> 4) << 3)) << 1;
      short8 af[4], bfr[4];
      #pragma unroll
      for (int i = 0; i < 4; ++i) {
        int row = wr * 64 + i * 16 + (lane & 15);
        int byte = ((row << 7) + kb) ^ ((row & 7) << 4);
        af[i] = *reinterpret_cast<const short8*>((const char*)(&As[cur][0]) + byte);
      }
      #pragma unroll
      for (int j = 0; j < 4; ++j) {
        int row = wc * 64 + j * 16 + (lane & 15);
        int byte = ((row << 7) + kb) ^ ((row & 7) << 4);
        bfr[j] = *reinterpret_cast<const short8*>((const char*)(&Bs[cur][0]) + byte);
      }
      __builtin_amdgcn_s_setprio(1);
      #pragma unroll
      for (int i = 0; i < 4; ++i)
        #pragma unroll
        for (int j = 0; j < 4; ++j)
          acc[i][j] = mfma16(af[i], bfr[j], acc[i][j]);
      __builtin_amdgcn_s_setprio(0);
    }
    __syncthreads();
    cur ^= 1;
  }

  #pragma unroll
  for (int j = 0; j < 4; ++j) {
    int col = bn + wc * 64 + j * 16 + (lane & 15);
    float bv = bias[col];
    #pragma unroll
    for (int i = 0; i < 4; ++i) {
      int row0 = bm + wr * 64 + i * 16 + ((lane >> 4) << 2);
      #pragma unroll
      for (int r = 0; r < 4; ++r) {
        float v = (acc[i][j][r] + bv) * alpha;
        if constexpr (OUT_F32)
          ((float*)Cp)[(size_t)(row0 + r) * N + col] = v;
        else
          ((short*)Cp)[(size_t)(row0 + r) * N + col] = bf16r(v);
      }
    }
  }
}

// ---------------- flash attention, 8-warp swapped-QK^T (R13 VERBATIM — green) ----------------
// Q: (B,T,H*64) bf16 pre-scaled by SCALE*log2e. K/V: (B,T,G*64) bf16. O: (B,T,H*64) bf16.
// Per block: 256 q-rows (8 warps x 32), KVBLK=64, 32x32x16 MFMA.
// S^T = mfma(K, Q): col=q=lane&31 -> lane-local softmax state (m,l).
// This kernel sits EXACTLY at VGPR=64 (the m69 occupancy cliff) — any change
// costing registers loses. See session ledger at top of file.
__global__ __launch_bounds__(512) void k_attn(
    const short* __restrict__ Q, const short* __restrict__ Kg,
    const short* __restrict__ Vg, short* __restrict__ Op)
{
  constexpr int T = 2048;
  constexpr int NT = T / 64;

  // bijective XCD-chunked swizzle: 512 blocks -> 64 contiguous per XCD
  const int orig = blockIdx.x;
  const int wgid = (orig & 7) * 64 + (orig >> 3);
  const int bh = wgid >> 3;            // 0..63 = b*32+h
  const int qb = wgid & 7;
  const int b = bh >> 5, h = bh & 31;
  const int g = h >> 2;
  const int q0 = qb * 256;

  const int t = threadIdx.x;
  const int lane = t & 63;
  const int wid = t >> 6;
  const int lo = lane & 31;
  const int hi = lane >> 5;

  __shared__ alignas(16) union {
    struct {
      short Kl[2][64 * 64];   // [key][d], XOR-swizzled bytes, gload_lds staged
      short Vt[2][64 * 72];   // [d][key], stride 72, reg-staged transpose
    } s;
    short Ol[8][32 * 72];     // epilogue O transpose, per-warp
  } sm;

  // Q fragments (B-operand): lane holds Q[q0w+lo][s*16 + hi*8 .. +8]
  const size_t qrow = (size_t)(b * T + q0 + wid * 32 + lo);
  short8 qf[4];
  #pragma unroll
  for (int s = 0; s < 4; ++s)
    qf[s] = *reinterpret_cast<const short8*>(Q + qrow * 2048 + h * 64 + s * 16 + hi * 8);

  f32x16 o0, o1;
  #pragma unroll
  for (int r = 0; r < 16; ++r) { o0[r] = 0.f; o1[r] = 0.f; }
  float m = -10000.f, l = 0.f;

  const short* Kbase = Kg + (size_t)(b * T) * 512 + g * 64;
  const short* Vbase = Vg + (size_t)(b * T) * 512 + g * 64;

  auto stageK = [&](int buf, int k0) {
    int lin = t * 16;                            // linear LDS byte dest
    int a = lin ^ (((lin >> 7) & 7) << 4);       // inverse-swizzled logical src
    int row = a >> 7;
    int col = (a & 127) >> 1;
    gload_lds16(Kbase + (size_t)(k0 + row) * 512 + col,
                (char*)(&sm.s.Kl[buf][0]) + (wid << 10));
  };
  short8 vreg;
  auto loadV = [&](int k0) {
    // thread t: key=lane, d-chunk=wid*8 (16B per lane)
    vreg = *reinterpret_cast<const short8*>(
        Vbase + (size_t)(k0 + lane) * 512 + wid * 8);
  };
  auto writeV = [&](int buf) {
    // V^T[d][key]: lanes write consecutive keys -> conflict-free
    #pragma unroll
    for (int e = 0; e < 8; ++e)
      sm.s.Vt[buf][(wid * 8 + e) * 72 + lane] = vreg[e];
  };

  stageK(0, 0);
  loadV(0);
  writeV(0);
  __syncthreads();

  int cur = 0;
  for (int kt = 0; kt < NT; ++kt) {
    const bool pf = (kt + 1 < NT);
    if (pf) { stageK(cur ^ 1, (kt + 1) * 64); loadV((kt + 1) * 64); }

    // ---- K frags (A-operand) + QK^T ----
    short8 kf[2][4];
    #pragma unroll
    for (int tt = 0; tt < 2; ++tt)
      #pragma unroll
      for (int s = 0; s < 4; ++s) {
        int row = tt * 32 + lo;
        int byte = ((row << 7) + (s << 5) + (hi << 4)) ^ ((row & 7) << 4);
        kf[tt][s] = *reinterpret_cast<const short8*>((const char*)(&sm.s.Kl[cur][0]) + byte);
      }
    f32x16 st0, st1;
    #pragma unroll
    for (int r = 0; r < 16; ++r) { st0[r] = 0.f; st1[r] = 0.f; }
    #pragma unroll
    for (int s = 0; s < 4; ++s) {
      st0 = mfma32(kf[0][s], qf[s], st0);
      st1 = mfma32(kf[1][s], qf[s], st1);
    }

    // ---- online softmax (log2 domain), lane-local q ----
    float mx = st0[0];
    #pragma unroll
    for (int r = 1; r < 16; ++r) mx = fmaxf(mx, st0[r]);
    #pragma unroll
    for (int r = 0; r < 16; ++r) mx = fmaxf(mx, st1[r]);
    mx = fmaxf(mx, __shfl_xor(mx, 32));
    if (!__all(mx - m <= 8.0f)) {      // T13 defer-max
      float mn = fmaxf(m, mx);
      float sc = fexp2(m - mn);
      m = mn; l *= sc;
      o0 = o0 * sc; o1 = o1 * sc;
    }
    float ssum = 0.f;
    #pragma unroll
    for (int r = 0; r < 16; ++r) { float e = fexp2(st0[r] - m); st0[r] = e; ssum += e; }
    #pragma unroll
    for (int r = 0; r < 16; ++r) { float e = fexp2(st1[r] - m); st1[r] = e; ssum += e; }
    ssum += __shfl_xor(ssum, 32);
    l += ssum;

    // ---- P -> bf16 B-frags: cvt_pk + cross-half shfl_xor redistribution ----
    short8 pb[4];
    #pragma unroll
    for (int tt = 0; tt < 2; ++tt) {
      const f32x16& sv = tt ? st1 : st0;
      #pragma unroll
      for (int half = 0; half < 2; ++half) {
        unsigned x1 = cvtpk(sv[half * 8 + 0], sv[half * 8 + 1]);
        unsigned x2 = cvtpk(sv[half * 8 + 2], sv[half * 8 + 3]);
        unsigned x3 = cvtpk(sv[half * 8 + 4], sv[half * 8 + 5]);
        unsigned x4 = cvtpk(sv[half * 8 + 6], sv[half * 8 + 7]);
        unsigned y1 = __shfl_xor(x1, 32);
        unsigned y2 = __shfl_xor(x2, 32);
        unsigned y3 = __shfl_xor(x3, 32);
        unsigned y4 = __shfl_xor(x4, 32);
        union { unsigned u[4]; short8 s8; } p;
        p.u[0] = hi ? y3 : x1;
        p.u[1] = hi ? y4 : x2;
        p.u[2] = hi ? x3 : y1;
        p.u[3] = hi ? x4 : y2;
        pb[tt * 2 + half] = p.s8;
      }
    }

    // ---- V^T frags (A-operand) + PV ----
    #pragma unroll
    for (int ks = 0; ks < 4; ++ks) {
      {
        int byte = (lo * 144) + (ks << 5) + (hi << 4);
        short8 va = *reinterpret_cast<const short8*>((const char*)(&sm.s.Vt[cur][0]) + byte);
        o0 = mfma32(va, pb[ks], o0);
      }
      {
        int byte = ((32 + lo) * 144) + (ks << 5) + (hi << 4);
        short8 va = *reinterpret_cast<const short8*>((const char*)(&sm.s.Vt[cur][0]) + byte);
        o1 = mfma32(va, pb[ks], o1);
      }
    }

    if (pf) writeV(cur ^ 1);
    __syncthreads();
    cur ^= 1;
  }

  // ---- epilogue: normalize, transpose via LDS, coalesced store ----
  float inv = 1.0f / l;
  #pragma unroll
  for (int dt = 0; dt < 2; ++dt) {
    const f32x16& ov = dt ? o1 : o0;
    #pragma unroll
    for (int r = 0; r < 16; r += 2) {
      unsigned d2 = cvtpk(ov[r] * inv, ov[r + 1] * inv);
      int dpos = dt * 32 + (r & 3) + 8 * (r >> 2) + 4 * hi;   // even
      *reinterpret_cast<unsigned*>((char*)(&sm.Ol[wid][0]) + (lo * 72 + dpos) * 2) = d2;
    }
  }
  __syncthreads();
  #pragma unroll
  for (int i = 0; i < 4; ++i) {
    int c = hi * 4 + i;
    short8 v = *reinterpret_cast<const short8*>((const char*)(&sm.Ol[wid][0]) + lo * 144 + c * 16);
    *reinterpret_cast<short8*>(Op + qrow * 2048 + h * 64 + c * 8) = v;
  }
}

// ---------------- launch ----------------
// Workspace (62914560 B):
//   [0..8M) q_wb  [8M..10M) k_wb  [10M..12M) v_wb  [12M..20M) o_wb
//   R1 [20M..36M): kx -> Ap (attn out)
//   R2 [36M..52M): vx
//   [52M..56M) Kp   [56M..60M) Vp
// d_out (33.5 MB fp32 out) doubles as scratch BEFORE O-proj:
//   qx = d_out[0..16M) bf16, Qp = d_out[16M..32M) bf16 — O-proj fully overwrites.
// GEMMs stay in SEPARATE dispatches (R15: merging destroys L2 locality).
extern "C" void kernel_launch(void* const* d_in, const int* in_sizes, int n_in,
                              void* d_out, int out_size, void* d_ws, size_t ws_size,
                              hipStream_t stream)
{
  const float* query = (const float*)d_in[0];
  const float* key   = (const float*)d_in[1];
  const float* value = (const float*)d_in[2];
  const float* q_w   = (const float*)d_in[3];
  const float* q_b   = (const float*)d_in[4];
  const float* k_w   = (const float*)d_in[5];
  const float* k_b   = (const float*)d_in[6];
  const float* v_w   = (const float*)d_in[7];
  const float* v_b   = (const float*)d_in[8];
  const float* o_w   = (const float*)d_in[9];
  const float* o_b   = (const float*)d_in[10];
  float* out = (float*)d_out;

  char* ws = (char*)d_ws;
  short* q_wb = (short*)(ws);
  short* k_wb = (short*)(ws + 8388608);
  short* v_wb = (short*)(ws + 10485760);
  short* o_wb = (short*)(ws + 12582912);
  short* R1   = (short*)(ws + 20971520);   // kx -> Ap
  short* R2   = (short*)(ws + 37748736);   // vx
  short* Kp   = (short*)(ws + 54525952);
  short* Vp   = (short*)(ws + 58720256);

  short* qx = (short*)d_out;                       // 16777216 B
  short* Qp = (short*)((char*)d_out + 16777216);   // 16777216 B

  const float ALPHA_Q = 0.125f * 1.4426950408889634f;  // SCALE * log2(e)

  // ALL 7 fp32->bf16 conversions in ONE dispatch (independent elementwise)
  k_cvt7<<<dim3(8192, 1, 7), 256, 0, stream>>>(
      q_w, q_wb, o_w, o_wb, k_w, k_wb, v_w, v_wb,
      query, qx, key, R1, value, R2);

  // Q-proj (qx@d_out -> Qp@d_out)
  k_gemm<false, false><<<dim3(16, 32), 256, 0, stream>>>(
      qx, q_wb, q_b, Qp, nullptr, nullptr, nullptr, nullptr, 4096, 2048, 2048, ALPHA_Q);

  // fused K-proj / V-proj (R1,R2 -> Kp,Vp)
  k_gemm<false, true><<<dim3(4, 32, 2), 256, 0, stream>>>(
      R1, k_wb, k_b, Kp, R2, v_wb, v_b, Vp, 4096, 512, 2048, 1.0f);

  // attention (Qp@d_out, Kp, Vp -> Ap@R1; kx dead)
  k_attn<<<dim3(512), dim3(512), 0, stream>>>(Qp, Kp, Vp, R1);

  // O-proj (Ap@R1 -> out; overwrites ALL of d_out)
  k_gemm<true, false><<<dim3(16, 32), 256, 0, stream>>>(
      R1, o_wb, o_b, out, nullptr, nullptr, nullptr, nullptr, 4096, 2048, 2048, 1.0f);
}

// Round 17
// 247.635 us; speedup vs baseline: 1.1139x; 1.0345x over previous
//
#include <hip/hip_runtime.h>
#include <stdint.h>
#include <stddef.h>

using short8 = __attribute__((ext_vector_type(8))) short;
using short4v = __attribute__((ext_vector_type(4))) short;
using f32x4  = __attribute__((ext_vector_type(4))) float;
using f32x16 = __attribute__((ext_vector_type(16))) float;
using bf16x8 = __attribute__((ext_vector_type(8))) __bf16;

#define DEVI __device__ __forceinline__

// SESSION LEDGER (refuted — do not re-try without new theory/hardware probe):
//  * v_permlane32_swap_b32 inline asm: failed BOTH operand orders (R2 0.575,
//    R14 0.628). Use __shfl_xor(.,32) — green R3/R8/R9/R13.
//  * fixed-m=0 softmax in 8-warp attn: fails ~0.04 (R5-R7); fine in 4-warp (R4).
//  * attn S-ahead pipeline: VGPR spill (R10). attn setprio: lockstep loss (R11).
//  * attn tree reductions: +4 VGPR crosses 64-VGPR cliff, occ 35->21% (R12).
//  * QKV GEMM merge: L2 thrash, FETCH 40->137MB, 71->116 µs (R15).
//  * cvt7 one-dispatch merge: over-provisioned grid, +3 µs (R16). Keep split.
//  * GEMM setprio removed this round per m190 + R11/R12 lockstep mechanism.

// round-to-nearest-even fp32 -> bf16 (bit pattern as short)
DEVI short bf16r(float f) {
  union { float f; uint32_t u; } x; x.f = f;
  uint32_t r = x.u + 0x7FFFu + ((x.u >> 16) & 1u);
  return (short)(r >> 16);
}

DEVI f32x4 mfma16(short8 a, short8 b, f32x4 c) {
  return __builtin_amdgcn_mfma_f32_16x16x32_bf16(
      __builtin_bit_cast(bf16x8, a), __builtin_bit_cast(bf16x8, b), c, 0, 0, 0);
}

DEVI f32x16 mfma32(short8 a, short8 b, f32x16 c) {
  return __builtin_amdgcn_mfma_f32_32x32x16_bf16(
      __builtin_bit_cast(bf16x8, a), __builtin_bit_cast(bf16x8, b), c, 0, 0, 0);
}

DEVI void gload_lds16(const void* g, void* l) {
  __builtin_amdgcn_global_load_lds(
      (const void __attribute__((address_space(1)))*)g,
      (void __attribute__((address_space(3)))*)l,
      16, 0, 0);
}

// v_exp_f32 computes 2^x
DEVI float fexp2(float x) {
  float r;
  asm("v_exp_f32 %0, %1" : "=v"(r) : "v"(x));
  return r;
}

// packed fp32->bf16: dst[15:0]=bf16(a), dst[31:16]=bf16(b)
DEVI unsigned cvtpk(float a, float b) {
  unsigned r;
  asm("v_cvt_pk_bf16_f32 %0, %1, %2" : "=v"(r) : "v"(a), "v"(b));
  return r;
}

// ---------------- fp32 -> bf16 conversions (R12/R13 split — validated) ----------------
// 4 weight tensors in one dispatch: z in 0..3; z<2 big (n_big), z>=2 small (n_small)
__global__ void k_cvtw(const float* __restrict__ s0, short* __restrict__ d0,
                       const float* __restrict__ s1, short* __restrict__ d1,
                       const float* __restrict__ s2, short* __restrict__ d2,
                       const float* __restrict__ s3, short* __restrict__ d3,
                       int n_big, int n_small) {
  const int z = blockIdx.z;
  const float* s = (z == 0) ? s0 : (z == 1) ? s1 : (z == 2) ? s2 : s3;
  short* d = (z == 0) ? d0 : (z == 1) ? d1 : (z == 2) ? d2 : d3;
  const int n = (z < 2) ? n_big : n_small;
  int i = blockIdx.x * blockDim.x + threadIdx.x;
  if (i < n) {
    f32x4 v = reinterpret_cast<const f32x4*>(s)[i];
    short4v o;
    o[0] = bf16r(v[0]); o[1] = bf16r(v[1]); o[2] = bf16r(v[2]); o[3] = bf16r(v[3]);
    reinterpret_cast<short4v*>(d)[i] = o;
  }
}

// 3 activation tensors (query/key/value), same size, z selects
__global__ void k_cvta(const float* __restrict__ s0, short* __restrict__ d0,
                       const float* __restrict__ s1, short* __restrict__ d1,
                       const float* __restrict__ s2, short* __restrict__ d2, int n4) {
  const int z = blockIdx.z;
  const float* s = (z == 0) ? s0 : (z == 1) ? s1 : s2;
  short* d = (z == 0) ? d0 : (z == 1) ? d1 : d2;
  int i = blockIdx.x * blockDim.x + threadIdx.x;
  if (i < n4) {
    f32x4 v = reinterpret_cast<const f32x4*>(s)[i];
    short4v o;
    o[0] = bf16r(v[0]); o[1] = bf16r(v[1]); o[2] = bf16r(v[2]); o[3] = bf16r(v[3]);
    reinterpret_cast<short4v*>(d)[i] = o;
  }
}

// ---------------- GEMM: C(M,N) = (A(M,K)bf16 @ W(N,K)^T + bias) * alpha ----------------
// R9 structure; setprio REMOVED (m190: negative on barrier-lockstep GEMM;
// same mechanism as R11->R12's attn A/B). No numerics/register change.
template<bool OUT_F32, bool DUAL>
__global__ __launch_bounds__(256) void k_gemm(
    const short* __restrict__ Aw, const short* __restrict__ Bw,
    const float* __restrict__ bias, void* __restrict__ Cp,
    const short* __restrict__ Aw2, const short* __restrict__ Bw2,
    const float* __restrict__ bias2, void* __restrict__ Cp2,
    int M, int N, int K, float alpha)
{
  if constexpr (DUAL) {
    if (blockIdx.z) { Aw = Aw2; Bw = Bw2; bias = bias2; Cp = Cp2; }
  }
  __shared__ short As[2][128 * 64];
  __shared__ short Bs[2][128 * 64];
  const int t = threadIdx.x;
  const int lane = t & 63;
  const int wid = t >> 6;
  const int wr = wid >> 1, wc = wid & 1;
  const int bm = blockIdx.y * 128;
  const int bn = blockIdx.x * 128;

  f32x4 acc[4][4];
  #pragma unroll
  for (int i = 0; i < 4; ++i)
    #pragma unroll
    for (int j = 0; j < 4; ++j) acc[i][j] = f32x4{0.f, 0.f, 0.f, 0.f};

  const int nt = K >> 6;

  auto stage = [&](const short* G, short (&buf)[128 * 64], int k0) {
    #pragma unroll
    for (int i = 0; i < 4; ++i) {
      int lin = t * 16 + i * 4096;
      int a = lin ^ (((lin >> 7) & 7) << 4);
      int row = a >> 7;
      int col = (a & 127) >> 1;
      const short* g = G + (size_t)row * K + k0 + col;
      gload_lds16(g, (char*)(&buf[0]) + (wid << 10) + (i << 12));
    }
  };

  stage(Aw + (size_t)bm * K, As[0], 0);
  stage(Bw + (size_t)bn * K, Bs[0], 0);
  __syncthreads();

  int cur = 0;
  for (int kt = 0; kt < nt; ++kt) {
    const bool pf = (kt + 1 < nt);
    if (pf) {
      stage(Aw + (size_t)bm * K, As[cur ^ 1], (kt + 1) << 6);
      stage(Bw + (size_t)bn * K, Bs[cur ^ 1], (kt + 1) << 6);
    }
    #pragma unroll
    for (int kk = 0; kk < 2; ++kk) {
      const int kb = (kk * 32 + ((lane >> 4) << 3)) << 1;
      short8 af[4], bfr[4];
      #pragma unroll
      for (int i = 0; i < 4; ++i) {
        int row = wr * 64 + i * 16 + (lane & 15);
        int byte = ((row << 7) + kb) ^ ((row & 7) << 4);
        af[i] = *reinterpret_cast<const short8*>((const char*)(&As[cur][0]) + byte);
      }
      #pragma unroll
      for (int j = 0; j < 4; ++j) {
        int row = wc * 64 + j * 16 + (lane & 15);
        int byte = ((row << 7) + kb) ^ ((row & 7) << 4);
        bfr[j] = *reinterpret_cast<const short8*>((const char*)(&Bs[cur][0]) + byte);
      }
      #pragma unroll
      for (int i = 0; i < 4; ++i)
        #pragma unroll
        for (int j = 0; j < 4; ++j)
          acc[i][j] = mfma16(af[i], bfr[j], acc[i][j]);
    }
    __syncthreads();
    cur ^= 1;
  }

  #pragma unroll
  for (int j = 0; j < 4; ++j) {
    int col = bn + wc * 64 + j * 16 + (lane & 15);
    float bv = bias[col];
    #pragma unroll
    for (int i = 0; i < 4; ++i) {
      int row0 = bm + wr * 64 + i * 16 + ((lane >> 4) << 2);
      #pragma unroll
      for (int r = 0; r < 4; ++r) {
        float v = (acc[i][j][r] + bv) * alpha;
        if constexpr (OUT_F32)
          ((float*)Cp)[(size_t)(row0 + r) * N + col] = v;
        else
          ((short*)Cp)[(size_t)(row0 + r) * N + col] = bf16r(v);
      }
    }
  }
}

// ---------------- flash attention, 8-warp swapped-QK^T (R13 VERBATIM — green) ----------------
// Q: (B,T,H*64) bf16 pre-scaled by SCALE*log2e. K/V: (B,T,G*64) bf16. O: (B,T,H*64) bf16.
// Per block: 256 q-rows (8 warps x 32), KVBLK=64, 32x32x16 MFMA.
// S^T = mfma(K, Q): col=q=lane&31 -> lane-local softmax state (m,l).
// This kernel sits EXACTLY at VGPR=64 (the m69 occupancy cliff) — any change
// costing registers loses. See session ledger at top of file.
__global__ __launch_bounds__(512) void k_attn(
    const short* __restrict__ Q, const short* __restrict__ Kg,
    const short* __restrict__ Vg, short* __restrict__ Op)
{
  constexpr int T = 2048;
  constexpr int NT = T / 64;

  // bijective XCD-chunked swizzle: 512 blocks -> 64 contiguous per XCD
  const int orig = blockIdx.x;
  const int wgid = (orig & 7) * 64 + (orig >> 3);
  const int bh = wgid >> 3;            // 0..63 = b*32+h
  const int qb = wgid & 7;
  const int b = bh >> 5, h = bh & 31;
  const int g = h >> 2;
  const int q0 = qb * 256;

  const int t = threadIdx.x;
  const int lane = t & 63;
  const int wid = t >> 6;
  const int lo = lane & 31;
  const int hi = lane >> 5;

  __shared__ alignas(16) union {
    struct {
      short Kl[2][64 * 64];   // [key][d], XOR-swizzled bytes, gload_lds staged
      short Vt[2][64 * 72];   // [d][key], stride 72, reg-staged transpose
    } s;
    short Ol[8][32 * 72];     // epilogue O transpose, per-warp
  } sm;

  // Q fragments (B-operand): lane holds Q[q0w+lo][s*16 + hi*8 .. +8]
  const size_t qrow = (size_t)(b * T + q0 + wid * 32 + lo);
  short8 qf[4];
  #pragma unroll
  for (int s = 0; s < 4; ++s)
    qf[s] = *reinterpret_cast<const short8*>(Q + qrow * 2048 + h * 64 + s * 16 + hi * 8);

  f32x16 o0, o1;
  #pragma unroll
  for (int r = 0; r < 16; ++r) { o0[r] = 0.f; o1[r] = 0.f; }
  float m = -10000.f, l = 0.f;

  const short* Kbase = Kg + (size_t)(b * T) * 512 + g * 64;
  const short* Vbase = Vg + (size_t)(b * T) * 512 + g * 64;

  auto stageK = [&](int buf, int k0) {
    int lin = t * 16;                            // linear LDS byte dest
    int a = lin ^ (((lin >> 7) & 7) << 4);       // inverse-swizzled logical src
    int row = a >> 7;
    int col = (a & 127) >> 1;
    gload_lds16(Kbase + (size_t)(k0 + row) * 512 + col,
                (char*)(&sm.s.Kl[buf][0]) + (wid << 10));
  };
  short8 vreg;
  auto loadV = [&](int k0) {
    // thread t: key=lane, d-chunk=wid*8 (16B per lane)
    vreg = *reinterpret_cast<const short8*>(
        Vbase + (size_t)(k0 + lane) * 512 + wid * 8);
  };
  auto writeV = [&](int buf) {
    // V^T[d][key]: lanes write consecutive keys -> conflict-free
    #pragma unroll
    for (int e = 0; e < 8; ++e)
      sm.s.Vt[buf][(wid * 8 + e) * 72 + lane] = vreg[e];
  };

  stageK(0, 0);
  loadV(0);
  writeV(0);
  __syncthreads();

  int cur = 0;
  for (int kt = 0; kt < NT; ++kt) {
    const bool pf = (kt + 1 < NT);
    if (pf) { stageK(cur ^ 1, (kt + 1) * 64); loadV((kt + 1) * 64); }

    // ---- K frags (A-operand) + QK^T ----
    short8 kf[2][4];
    #pragma unroll
    for (int tt = 0; tt < 2; ++tt)
      #pragma unroll
      for (int s = 0; s < 4; ++s) {
        int row = tt * 32 + lo;
        int byte = ((row << 7) + (s << 5) + (hi << 4)) ^ ((row & 7) << 4);
        kf[tt][s] = *reinterpret_cast<const short8*>((const char*)(&sm.s.Kl[cur][0]) + byte);
      }
    f32x16 st0, st1;
    #pragma unroll
    for (int r = 0; r < 16; ++r) { st0[r] = 0.f; st1[r] = 0.f; }
    #pragma unroll
    for (int s = 0; s < 4; ++s) {
      st0 = mfma32(kf[0][s], qf[s], st0);
      st1 = mfma32(kf[1][s], qf[s], st1);
    }

    // ---- online softmax (log2 domain), lane-local q ----
    float mx = st0[0];
    #pragma unroll
    for (int r = 1; r < 16; ++r) mx = fmaxf(mx, st0[r]);
    #pragma unroll
    for (int r = 0; r < 16; ++r) mx = fmaxf(mx, st1[r]);
    mx = fmaxf(mx, __shfl_xor(mx, 32));
    if (!__all(mx - m <= 8.0f)) {      // T13 defer-max
      float mn = fmaxf(m, mx);
      float sc = fexp2(m - mn);
      m = mn; l *= sc;
      o0 = o0 * sc; o1 = o1 * sc;
    }
    float ssum = 0.f;
    #pragma unroll
    for (int r = 0; r < 16; ++r) { float e = fexp2(st0[r] - m); st0[r] = e; ssum += e; }
    #pragma unroll
    for (int r = 0; r < 16; ++r) { float e = fexp2(st1[r] - m); st1[r] = e; ssum += e; }
    ssum += __shfl_xor(ssum, 32);
    l += ssum;

    // ---- P -> bf16 B-frags: cvt_pk + cross-half shfl_xor redistribution ----
    short8 pb[4];
    #pragma unroll
    for (int tt = 0; tt < 2; ++tt) {
      const f32x16& sv = tt ? st1 : st0;
      #pragma unroll
      for (int half = 0; half < 2; ++half) {
        unsigned x1 = cvtpk(sv[half * 8 + 0], sv[half * 8 + 1]);
        unsigned x2 = cvtpk(sv[half * 8 + 2], sv[half * 8 + 3]);
        unsigned x3 = cvtpk(sv[half * 8 + 4], sv[half * 8 + 5]);
        unsigned x4 = cvtpk(sv[half * 8 + 6], sv[half * 8 + 7]);
        unsigned y1 = __shfl_xor(x1, 32);
        unsigned y2 = __shfl_xor(x2, 32);
        unsigned y3 = __shfl_xor(x3, 32);
        unsigned y4 = __shfl_xor(x4, 32);
        union { unsigned u[4]; short8 s8; } p;
        p.u[0] = hi ? y3 : x1;
        p.u[1] = hi ? y4 : x2;
        p.u[2] = hi ? x3 : y1;
        p.u[3] = hi ? x4 : y2;
        pb[tt * 2 + half] = p.s8;
      }
    }

    // ---- V^T frags (A-operand) + PV ----
    #pragma unroll
    for (int ks = 0; ks < 4; ++ks) {
      {
        int byte = (lo * 144) + (ks << 5) + (hi << 4);
        short8 va = *reinterpret_cast<const short8*>((const char*)(&sm.s.Vt[cur][0]) + byte);
        o0 = mfma32(va, pb[ks], o0);
      }
      {
        int byte = ((32 + lo) * 144) + (ks << 5) + (hi << 4);
        short8 va = *reinterpret_cast<const short8*>((const char*)(&sm.s.Vt[cur][0]) + byte);
        o1 = mfma32(va, pb[ks], o1);
      }
    }

    if (pf) writeV(cur ^ 1);
    __syncthreads();
    cur ^= 1;
  }

  // ---- epilogue: normalize, transpose via LDS, coalesced store ----
  float inv = 1.0f / l;
  #pragma unroll
  for (int dt = 0; dt < 2; ++dt) {
    const f32x16& ov = dt ? o1 : o0;
    #pragma unroll
    for (int r = 0; r < 16; r += 2) {
      unsigned d2 = cvtpk(ov[r] * inv, ov[r + 1] * inv);
      int dpos = dt * 32 + (r & 3) + 8 * (r >> 2) + 4 * hi;   // even
      *reinterpret_cast<unsigned*>((char*)(&sm.Ol[wid][0]) + (lo * 72 + dpos) * 2) = d2;
    }
  }
  __syncthreads();
  #pragma unroll
  for (int i = 0; i < 4; ++i) {
    int c = hi * 4 + i;
    short8 v = *reinterpret_cast<const short8*>((const char*)(&sm.Ol[wid][0]) + lo * 144 + c * 16);
    *reinterpret_cast<short8*>(Op + qrow * 2048 + h * 64 + c * 8) = v;
  }
}

// ---------------- launch (R13's validated dataflow) ----------------
// Workspace (62914560 B):
//   [0..8M) q_wb  [8M..10M) k_wb  [10M..12M) v_wb  [12M..20M) o_wb
//   R1 [20M..36M): kx -> Ap (attn out)
//   R2 [36M..52M): vx
//   [52M..56M) Kp   [56M..60M) Vp
// d_out (33.5 MB fp32 out) doubles as scratch BEFORE O-proj:
//   qx = d_out[0..16M) bf16, Qp = d_out[16M..32M) bf16 — O-proj fully overwrites.
// GEMMs stay in SEPARATE dispatches (R15: merging destroys L2 locality).
extern "C" void kernel_launch(void* const* d_in, const int* in_sizes, int n_in,
                              void* d_out, int out_size, void* d_ws, size_t ws_size,
                              hipStream_t stream)
{
  const float* query = (const float*)d_in[0];
  const float* key   = (const float*)d_in[1];
  const float* value = (const float*)d_in[2];
  const float* q_w   = (const float*)d_in[3];
  const float* q_b   = (const float*)d_in[4];
  const float* k_w   = (const float*)d_in[5];
  const float* k_b   = (const float*)d_in[6];
  const float* v_w   = (const float*)d_in[7];
  const float* v_b   = (const float*)d_in[8];
  const float* o_w   = (const float*)d_in[9];
  const float* o_b   = (const float*)d_in[10];
  float* out = (float*)d_out;

  char* ws = (char*)d_ws;
  short* q_wb = (short*)(ws);
  short* k_wb = (short*)(ws + 8388608);
  short* v_wb = (short*)(ws + 10485760);
  short* o_wb = (short*)(ws + 12582912);
  short* R1   = (short*)(ws + 20971520);   // kx -> Ap
  short* R2   = (short*)(ws + 37748736);   // vx
  short* Kp   = (short*)(ws + 54525952);
  short* Vp   = (short*)(ws + 58720256);

  short* qx = (short*)d_out;                       // 16777216 B
  short* Qp = (short*)((char*)d_out + 16777216);   // 16777216 B

  const float ALPHA_Q = 0.125f * 1.4426950408889634f;  // SCALE * log2(e)

  // all 4 weight cvts in one dispatch; all 3 activation cvts in one dispatch
  k_cvtw<<<dim3(4096, 1, 4), 256, 0, stream>>>(
      q_w, q_wb, o_w, o_wb, k_w, k_wb, v_w, v_wb, 1048576, 262144);
  k_cvta<<<dim3(8192, 1, 3), 256, 0, stream>>>(
      query, qx, key, R1, value, R2, 2097152);

  // Q-proj (qx@d_out -> Qp@d_out)
  k_gemm<false, false><<<dim3(16, 32), 256, 0, stream>>>(
      qx, q_wb, q_b, Qp, nullptr, nullptr, nullptr, nullptr, 4096, 2048, 2048, ALPHA_Q);

  // fused K-proj / V-proj (R1,R2 -> Kp,Vp)
  k_gemm<false, true><<<dim3(4, 32, 2), 256, 0, stream>>>(
      R1, k_wb, k_b, Kp, R2, v_wb, v_b, Vp, 4096, 512, 2048, 1.0f);

  // attention (Qp@d_out, Kp, Vp -> Ap@R1; kx dead)
  k_attn<<<dim3(512), dim3(512), 0, stream>>>(Qp, Kp, Vp, R1);

  // O-proj (Ap@R1 -> out; overwrites ALL of d_out)
  k_gemm<true, false><<<dim3(16, 32), 256, 0, stream>>>(
      R1, o_wb, o_b, out, nullptr, nullptr, nullptr, nullptr, 4096, 2048, 2048, 1.0f);
}